// Round 9
// baseline (585.063 us; speedup 1.0000x reference)
//
#include <hip/hip_runtime.h>
#include <hip/hip_bf16.h>

#define TOK 4096
#define DIM 1024
#define FFN_N 4096
#define SEQ 2048
#define HD 64
#define QKS 3072   // fused QKV row stride

using short8 = __attribute__((ext_vector_type(8))) short;
using short4v = __attribute__((ext_vector_type(4))) short;
using f32x4 = __attribute__((ext_vector_type(4))) float;

__device__ __forceinline__ short f2b(float f){
  return __builtin_bit_cast(short, __float2bfloat16(f));
}
__device__ __forceinline__ float b2f(short s){
  return __bfloat162float(__builtin_bit_cast(__hip_bfloat16, s));
}
__device__ __forceinline__ unsigned cvtpk(float lo, float hi){
  unsigned r;
  asm("v_cvt_pk_bf16_f32 %0, %1, %2" : "=v"(r) : "v"(lo), "v"(hi));
  return r;
}

__device__ __forceinline__ void gl_lds16(const short* g, short* l){
  __builtin_amdgcn_global_load_lds(
      (const __attribute__((address_space(1))) unsigned int*)g,
      (__attribute__((address_space(3))) unsigned int*)l, 16, 0, 0);
}

#define BARRAW() asm volatile("s_barrier" ::: "memory")
#define VMCNT(n) asm volatile("s_waitcnt vmcnt(" #n ")" ::: "memory")

// ---------------- cast f32 -> bf16 ----------------
__global__ __launch_bounds__(256) void castk(const float* __restrict__ src,
                                             short* __restrict__ dst, int n){
  int stride = gridDim.x*256*4;
  for (int i = (blockIdx.x*256 + threadIdx.x)*4; i < n; i += stride){
    float4 v = *reinterpret_cast<const float4*>(src + i);
    short4v o; o[0]=f2b(v.x); o[1]=f2b(v.y); o[2]=f2b(v.z); o[3]=f2b(v.w);
    *reinterpret_cast<short4v*>(dst + i) = o;
  }
}

// ---------------- layernorm f32 -> bf16 ----------------
__global__ __launch_bounds__(256) void lnk(const float* __restrict__ x,
                                           const float* __restrict__ g,
                                           const float* __restrict__ b,
                                           short* __restrict__ out){
  int row = blockIdx.x;
  int t = threadIdx.x;
  const float* xr = x + (size_t)row*DIM;
  float4 v = *reinterpret_cast<const float4*>(xr + t*4);
  float s = v.x+v.y+v.z+v.w;
  float s2 = v.x*v.x+v.y*v.y+v.z*v.z+v.w*v.w;
  #pragma unroll
  for (int off=1; off<64; off<<=1){ s += __shfl_xor(s,off); s2 += __shfl_xor(s2,off); }
  __shared__ float as_[4], as2_[4];
  if ((t&63)==0){ as_[t>>6]=s; as2_[t>>6]=s2; }
  __syncthreads();
  s = as_[0]+as_[1]+as_[2]+as_[3];
  s2 = as2_[0]+as2_[1]+as2_[2]+as2_[3];
  float mu = s * (1.0f/DIM);
  float var = s2 * (1.0f/DIM) - mu*mu;
  float r = rsqrtf(var + 1e-5f);
  float4 gv = *reinterpret_cast<const float4*>(g + t*4);
  float4 bv = *reinterpret_cast<const float4*>(b + t*4);
  short4v o;
  o[0]=f2b((v.x-mu)*r*gv.x + bv.x);
  o[1]=f2b((v.y-mu)*r*gv.y + bv.y);
  o[2]=f2b((v.z-mu)*r*gv.z + bv.z);
  o[3]=f2b((v.w-mu)*r*gv.w + bv.w);
  *reinterpret_cast<short4v*>(out + (size_t)row*DIM + t*4) = o;
}

// ---------------- GEMM C = A @ B^T (+epilogue), m97 structure (small-N shapes) ----------------
template<int MODE>
__global__ __launch_bounds__(256,2) void gemm_bt(
    const short* __restrict__ A, const short* __restrict__ Bt,
    short* __restrict__ Cb, float* __restrict__ Cf,
    const float* __restrict__ bias, const float* __restrict__ resid,
    const short* __restrict__ aux,
    int M, int N, int K)
{
  __shared__ __align__(16) short Al[128*32];
  __shared__ __align__(16) short Bl[128*32];
  const int tid = threadIdx.x, lane = tid & 63, w = tid >> 6;
  const int wr = w >> 1, wc = w & 1;
  const int bx = blockIdx.x, by = blockIdx.y;

  const short* ga0 = A  + (size_t)(by*128 + w*32 + (lane>>2))*K + (lane&3)*8;
  const short* gb0 = Bt + (size_t)(bx*128 + w*32 + (lane>>2))*K + (lane&3)*8;
  short* la0 = &Al[w*32*32];
  short* lb0 = &Bl[w*32*32];

  f32x4 acc[4][4] = {};

  for (int k0 = 0; k0 < K; k0 += 32){
    __syncthreads();
    gl_lds16(ga0 + k0,                 la0);
    gl_lds16(ga0 + k0 + (size_t)16*K,  la0 + 16*32);
    gl_lds16(gb0 + k0,                 lb0);
    gl_lds16(gb0 + k0 + (size_t)16*K,  lb0 + 16*32);
    __syncthreads();
    short8 af[4], bf[4];
    #pragma unroll
    for (int m=0;m<4;m++)
      af[m] = *reinterpret_cast<const short8*>(&Al[(wr*64 + m*16 + (lane&15))*32 + (lane>>4)*8]);
    #pragma unroll
    for (int n=0;n<4;n++)
      bf[n] = *reinterpret_cast<const short8*>(&Bl[(wc*64 + n*16 + (lane&15))*32 + (lane>>4)*8]);
    #pragma unroll
    for (int m=0;m<4;m++)
      #pragma unroll
      for (int n=0;n<4;n++)
        acc[m][n] = __builtin_amdgcn_mfma_f32_16x16x32_bf16(af[m], bf[n], acc[m][n], 0,0,0);
  }

  #pragma unroll
  for (int m=0;m<4;m++){
    #pragma unroll
    for (int n=0;n<4;n++){
      #pragma unroll
      for (int j=0;j<4;j++){
        int r = by*128 + wr*64 + m*16 + ((lane>>4)<<2) + j;
        int c = bx*128 + wc*64 + n*16 + (lane&15);
        float v = acc[m][n][j];
        if (MODE==1 || MODE==3) v += bias[c];
        size_t idx = (size_t)r*N + c;
        if (MODE==4){
          float a = b2f(aux[idx]);
          float sg = a / (1.0f + __expf(-a));
          Cb[idx] = f2b(sg * v);
        } else if (MODE<=1) {
          Cb[idx] = f2b(v);
        } else {
          Cf[idx] = resid[idx] + v;
        }
      }
    }
  }
}

// ---------------- 256x256 GEMM: 2 barriers/K-tile, counted vmcnt (unchanged from R8) ----------------
template<int MODE>
__global__ __launch_bounds__(512,2) void gemm256(
    const short* __restrict__ A, const short* __restrict__ Bt,
    short* __restrict__ Cb,
    const float* __restrict__ bias, const short* __restrict__ aux,
    int M, int N, int K)
{
  __shared__ __align__(16) short L[65536];
  const int tid = threadIdx.x, lane = tid&63, w = tid>>6;
  const int q15 = lane&15, h8 = lane>>4;
  const int wm = w>>2, wn = w&3;
  const int NT = K>>6;

  int bid = blockIdx.x;
  int wg = (bid&7)*(gridDim.x>>3) + (bid>>3);
  const int by = wg >> 4, bx = wg & 15;

  const int isub = w*8 + (lane>>3);
  const int koff = ((lane&7) ^ ((lane>>3)&7))*8;

  const short* gA[2][2]; const short* gB[2][2];
  #pragma unroll
  for (int hh=0; hh<2; hh++){
    #pragma unroll
    for (int j=0; j<2; j++){
      int i = j*64 + isub;
      int Ra = by*256 + (i>>6)*128 + hh*64 + (i&63);
      gA[hh][j] = A + (size_t)Ra*K + koff;
      int Rb = bx*256 + (i>>5)*64 + hh*32 + (i&31);
      gB[hh][j] = Bt + (size_t)Rb*K + koff;
    }
  }

  auto stA = [&](int db, int hh, int j, int kt){
    gl_lds16(gA[hh][j] + (size_t)kt*64, &L[db*32768 + hh*8192 + j*4096 + w*512]);
  };
  auto stB = [&](int db, int hh, int j, int kt){
    gl_lds16(gB[hh][j] + (size_t)kt*64, &L[db*32768 + (2+hh)*8192 + j*4096 + w*512]);
  };
  auto rdA = [&](int db, int mh, int m, int ks)->short8{
    int i = wm*64 + m*16 + q15;
    int ch = (ks*4 + h8) ^ (i&7);
    return *reinterpret_cast<const short8*>(&L[db*32768 + mh*8192 + i*64 + ch*8]);
  };
  auto rdB = [&](int db, int nh, int n, int ks)->short8{
    int i = wn*32 + n*16 + q15;
    int ch = (ks*4 + h8) ^ (i&7);
    return *reinterpret_cast<const short8*>(&L[db*32768 + (2+nh)*8192 + i*64 + ch*8]);
  };

  f32x4 acc[8][4] = {};
  short8 af[4][2], bf0[2][2], bf1[2][2];

#define MFMA_QUAD(MH, NH, BF)                                                  \
  __builtin_amdgcn_s_setprio(1);                                               \
  _Pragma("unroll")                                                            \
  for (int m=0;m<4;m++){                                                       \
    _Pragma("unroll")                                                          \
    for (int n=0;n<2;n++){                                                     \
      acc[(MH)*4+m][(NH)*2+n] = __builtin_amdgcn_mfma_f32_16x16x32_bf16(       \
          af[m][0], BF[n][0], acc[(MH)*4+m][(NH)*2+n], 0,0,0);                 \
      acc[(MH)*4+m][(NH)*2+n] = __builtin_amdgcn_mfma_f32_16x16x32_bf16(       \
          af[m][1], BF[n][1], acc[(MH)*4+m][(NH)*2+n], 0,0,0);                 \
    }                                                                          \
  }                                                                            \
  __builtin_amdgcn_s_setprio(0);

  stA(0,0,0,0); stA(0,0,1,0);
  stB(0,0,0,0); stB(0,0,1,0);
  stA(0,1,0,0); stA(0,1,1,0);
  stB(0,1,0,0); stB(0,1,1,0);
  VMCNT(4);
  BARRAW();

  for (int t = 0; t < NT; ++t){
    const int db = t&1;
    const bool pf = (t+1 < NT);

    #pragma unroll
    for (int m=0;m<4;m++){ af[m][0]=rdA(db,0,m,0); af[m][1]=rdA(db,0,m,1); }
    #pragma unroll
    for (int n=0;n<2;n++){ bf0[n][0]=rdB(db,0,n,0); bf0[n][1]=rdB(db,0,n,1); }
    if (pf){ stA(db^1,0,0,t+1); stA(db^1,0,1,t+1);
             stB(db^1,0,0,t+1); stB(db^1,0,1,t+1); }
    MFMA_QUAD(0,0,bf0);

    if (pf){ VMCNT(4); } else { VMCNT(0); }
    BARRAW();

    #pragma unroll
    for (int n=0;n<2;n++){ bf1[n][0]=rdB(db,1,n,0); bf1[n][1]=rdB(db,1,n,1); }
    if (pf){ stA(db^1,1,0,t+1); stA(db^1,1,1,t+1);
             stB(db^1,1,0,t+1); stB(db^1,1,1,t+1); }
    MFMA_QUAD(0,1,bf1);

    #pragma unroll
    for (int m=0;m<4;m++){ af[m][0]=rdA(db,1,m,0); af[m][1]=rdA(db,1,m,1); }
    MFMA_QUAD(1,1,bf1);
    MFMA_QUAD(1,0,bf0);

    if (pf){ VMCNT(4); }
    BARRAW();
  }

  #pragma unroll
  for (int mq=0;mq<8;mq++){
    #pragma unroll
    for (int nq=0;nq<4;nq++){
      #pragma unroll
      for (int jj=0;jj<4;jj++){
        int r = by*256 + wm*128 + mq*16 + h8*4 + jj;
        int c = bx*256 + wn*64  + nq*16 + q15;
        float v = acc[mq][nq][jj];
        if (MODE==1) v += bias[c];
        size_t idx = (size_t)r*N + c;
        if (MODE==4){
          float a = b2f(aux[idx]);
          float sg = a / (1.0f + __expf(-a));
          Cb[idx] = f2b(sg * v);
        } else {
          Cb[idx] = f2b(v);
        }
      }
    }
  }
#undef MFMA_QUAD
}

// ---------------- V transpose: per (b,h), [SEQ][QKS] -> [64][SEQ], chunk-swizzle baked ----------------
// Output: V'[d][seg*64 + (c^(d&7))*8 + j] = V[seg*64 + c*8 + j][d]  (c = 64-kv-local chunk)
__global__ __launch_bounds__(256) void vtrk(const short* __restrict__ V,
                                            short* __restrict__ Vt){
  __shared__ __align__(16) short T[64*72];
  const int tid = threadIdx.x;
  const int bh = blockIdx.y;
  const int b = bh >> 4, hd = bh & 15;
  const int t0 = blockIdx.x * 64;
  const short* src = V + (size_t)b*SEQ*QKS + (size_t)hd*HD;

  const int r = tid>>2, c = tid&3;
  short8 a0 = *reinterpret_cast<const short8*>(src + (size_t)(t0+r)*QKS + c*8);
  short8 a1 = *reinterpret_cast<const short8*>(src + (size_t)(t0+r)*QKS + (c+4)*8);
  *reinterpret_cast<short8*>(&T[r*72 + c*8]) = a0;
  *reinterpret_cast<short8*>(&T[r*72 + (c+4)*8]) = a1;
  __syncthreads();

  short* dst = Vt + (size_t)bh*HD*SEQ;
  #pragma unroll
  for (int dd=0; dd<2; dd++){
    int d = (tid>>3) + dd*32;
    int tc = tid&7;
    short8 o;
    #pragma unroll
    for (int j=0;j<8;j++) o[j] = T[(tc*8+j)*72 + d];
    *reinterpret_cast<short8*>(dst + (size_t)d*SEQ + t0 + ((tc ^ (d&7))*8)) = o;
  }
}

// ---------------- flash attention: KVBLK=128, double-buffered K/V, 1 barrier/tile ----------------
// K staged with per-lane source chunk-XOR; V' has swizzle baked (linear source).
// Per tile: issue 8 gl_lds for t+1 -> buf^1; compute two 64-kv sub-steps on buf;
// own vmcnt(0); s_barrier.  (T14 issue-early/wait-late + R7 publication rule.)
__global__ __launch_bounds__(256) void attnk(
    const short* __restrict__ Q, const short* __restrict__ K,
    const short* __restrict__ Vp, short* __restrict__ O)
{
  __shared__ __align__(16) short Kb[2][128*64];
  __shared__ __align__(16) short Vb[2][64*128];
  __shared__ __align__(16) short Pl[4*16*72];

  const int tid = threadIdx.x, lane = tid&63, w = tid>>6;
  const int h = lane>>4, q15 = lane&15;
  const int bh = blockIdx.y;
  const int b = bh >> 4, hd = bh & 15;
  const int q0 = blockIdx.x * 64;
  const size_t base  = (size_t)b*SEQ*QKS + (size_t)hd*HD;
  const size_t obase = (size_t)b*SEQ*DIM + (size_t)hd*HD;
  const size_t vbase = (size_t)bh*HD*SEQ;

  short8 aq[2];
  {
    int qrow = q0 + w*16 + q15;
    const short* qp = Q + base + (size_t)qrow*QKS + h*8;
    aq[0] = *reinterpret_cast<const short8*>(qp);
    aq[1] = *reinterpret_cast<const short8*>(qp + 32);
  }

  float mrun = -1e30f, lrun = 0.f;
  f32x4 o[4] = {};

  // K staging: 4 loads/wave; rows w*32 + (lane>>3) + i*8; source chunk XOR key (lane>>3)&7
  const short* kgp0 = K + base + (size_t)(w*32 + (lane>>3))*QKS
                        + ((lane&7) ^ ((lane>>3)&7))*8;
  // V staging: 4 loads/wave; d-rows w*16 + (lane>>4) + i*4; linear source (swizzle baked in V')
  const short* vgp0 = Vp + vbase + (size_t)(w*16 + (lane>>4))*SEQ + (lane&15)*8;

  short* plw = &Pl[w*16*72];
  const int xk = (q15&7);

  // prologue: stage tile 0 into buf 0
  #pragma unroll
  for (int i=0;i<4;i++) gl_lds16(kgp0 + (size_t)(i*8)*QKS, &Kb[0][(w*32 + i*8)*64]);
  #pragma unroll
  for (int i=0;i<4;i++) gl_lds16(vgp0 + (size_t)(i*4)*SEQ, &Vb[0][(w*16 + i*4)*128]);
  VMCNT(0);
  BARRAW();

  int db = 0;
  for (int kv0 = 0; kv0 < SEQ; kv0 += 128){
    const bool pf = (kv0 + 128 < SEQ);
    if (pf){
      #pragma unroll
      for (int i=0;i<4;i++)
        gl_lds16(kgp0 + (size_t)(kv0 + 128 + i*8)*QKS, &Kb[db^1][(w*32 + i*8)*64]);
      #pragma unroll
      for (int i=0;i<4;i++)
        gl_lds16(vgp0 + (size_t)(i*4)*SEQ + (kv0 + 128), &Vb[db^1][(w*16 + i*4)*128]);
    }

    #pragma unroll
    for (int sub=0; sub<2; sub++){
      const short* Kl = &Kb[db][sub*64*64];
      // QK^T (swapped): s[nt] rows = kv, col = q = q15
      f32x4 s[4];
      #pragma unroll
      for (int nt=0; nt<4; nt++){
        const short8 kf0 = *reinterpret_cast<const short8*>(
            &Kl[(nt*16+q15)*64 + ((h    ^ xk)*8)]);
        const short8 kf1 = *reinterpret_cast<const short8*>(
            &Kl[(nt*16+q15)*64 + (((4+h)^ xk)*8)]);
        f32x4 t = {};
        t = __builtin_amdgcn_mfma_f32_16x16x32_bf16(kf0, aq[0], t, 0,0,0);
        t = __builtin_amdgcn_mfma_f32_16x16x32_bf16(kf1, aq[1], t, 0,0,0);
        s[nt] = t * 0.125f;
      }

      float pm = s[0][0];
      #pragma unroll
      for (int nt=0; nt<4; nt++)
        #pragma unroll
        for (int j=0; j<4; j++) pm = fmaxf(pm, s[nt][j]);
      pm = fmaxf(pm, __shfl_xor(pm, 16));
      pm = fmaxf(pm, __shfl_xor(pm, 32));

      float mn = fmaxf(mrun, pm);
      float al = __expf(mrun - mn);
      mrun = mn;
      float rs = 0.f;
      #pragma unroll
      for (int nt=0; nt<4; nt++)
        #pragma unroll
        for (int j=0; j<4; j++){
          s[nt][j] = __expf(s[nt][j] - mn);
          rs += s[nt][j];
        }
      rs += __shfl_xor(rs, 16);
      rs += __shfl_xor(rs, 32);
      lrun = lrun*al + rs;

      float alj[4];
      #pragma unroll
      for (int j=0;j<4;j++) alj[j] = __shfl(al, 4*h + j);
      #pragma unroll
      for (int dt=0;dt<4;dt++)
        #pragma unroll
        for (int j=0;j<4;j++) o[dt][j] *= alj[j];

      #pragma unroll
      for (int nt=0;nt<4;nt++){
        uint2 u;
        u.x = cvtpk(s[nt][0], s[nt][1]);
        u.y = cvtpk(s[nt][2], s[nt][3]);
        *reinterpret_cast<uint2*>(&plw[q15*72 + nt*16 + 4*h]) = u;
      }
      asm volatile("s_waitcnt lgkmcnt(0)" ::: "memory");
      const short8 ap0 = *reinterpret_cast<const short8*>(&plw[q15*72 +      h*8]);
      const short8 ap1 = *reinterpret_cast<const short8*>(&plw[q15*72 + 32 + h*8]);

      #pragma unroll
      for (int dt=0;dt<4;dt++){
        const short8 vf0 = *reinterpret_cast<const short8*>(
            &Vb[db][(dt*16+q15)*128 + sub*64 + ((h    ^ xk)*8)]);
        const short8 vf1 = *reinterpret_cast<const short8*>(
            &Vb[db][(dt*16+q15)*128 + sub*64 + (((4+h)^ xk)*8)]);
        o[dt] = __builtin_amdgcn_mfma_f32_16x16x32_bf16(ap0, vf0, o[dt], 0,0,0);
        o[dt] = __builtin_amdgcn_mfma_f32_16x16x32_bf16(ap1, vf1, o[dt], 0,0,0);
      }
    }

    if (pf){ VMCNT(0); }
    BARRAW();
    db ^= 1;
  }

  float rl[4];
  #pragma unroll
  for (int j=0;j<4;j++) rl[j] = 1.0f / __shfl(lrun, 4*h + j);
  #pragma unroll
  for (int dt=0;dt<4;dt++)
    #pragma unroll
    for (int j=0;j<4;j++){
      int qrow = q0 + w*16 + 4*h + j;
      O[obase + (size_t)qrow*DIM + dt*16 + q15] = f2b(o[dt][j]*rl[j]);
    }
}

extern "C" void kernel_launch(void* const* d_in, const int* in_sizes, int n_in,
                              void* d_out, int out_size, void* d_ws, size_t ws_size,
                              hipStream_t stream) {
  const float* x     = (const float*)d_in[0];
  const float* ln1_g = (const float*)d_in[1];
  const float* ln1_b = (const float*)d_in[2];
  const float* q_w   = (const float*)d_in[3];
  const float* k_w   = (const float*)d_in[4];
  const float* v_w   = (const float*)d_in[5];
  const float* o_w   = (const float*)d_in[6];
  const float* ln2_g = (const float*)d_in[7];
  const float* ln2_b = (const float*)d_in[8];
  const float* fi_w  = (const float*)d_in[9];
  const float* fi_b  = (const float*)d_in[10];
  const float* sw_w  = (const float*)d_in[11];
  const float* sw_v  = (const float*)d_in[12];
  const float* fo_w  = (const float*)d_in[13];
  const float* fo_b  = (const float*)d_in[14];
  float* out = (float*)d_out;

  char* W = (char*)d_ws;
  const size_t MB = 1024*1024;
  short* qkvw = (short*)(W +   0*MB);   // fused [3072][1024]
  short* ow   = (short*)(W +   6*MB);
  short* fiw  = (short*)(W +   8*MB);
  short* sww  = (short*)(W +  16*MB);
  short* swv  = (short*)(W +  48*MB);
  short* fow  = (short*)(W +  80*MB);
  short* hb   = (short*)(W +  88*MB);
  short* qkv  = (short*)(W +  96*MB);   // [4096][3072] = 24MB
  short* ab   = (short*)(W + 120*MB);
  float* x2   = (float*)(W + 128*MB);
  short* ub   = (short*)(W + 144*MB);
  short* gb   = (short*)(W + 176*MB);
  short* a1   = (short*)(W +  96*MB);   // alias qkv+ab (dead by SwiGLU time)
  short* vt   = (short*)(W + 144*MB);   // alias ub (dead before FFN-in)

  dim3 blk(256);
  castk<<<1024,blk,0,stream>>>(q_w, qkvw,             1024*1024);
  castk<<<1024,blk,0,stream>>>(k_w, qkvw + 1024*1024, 1024*1024);
  castk<<<1024,blk,0,stream>>>(v_w, qkvw + 2048*1024, 1024*1024);
  castk<<<1024,blk,0,stream>>>(o_w, ow, 1024*1024);
  castk<<<2048,blk,0,stream>>>(fi_w, fiw, 4096*1024);
  castk<<<2048,blk,0,stream>>>(sw_w, sww, 4096*4096);
  castk<<<2048,blk,0,stream>>>(sw_v, swv, 4096*4096);
  castk<<<2048,blk,0,stream>>>(fo_w, fow, 1024*4096);

  lnk<<<TOK,blk,0,stream>>>(x, ln1_g, ln1_b, hb);
  gemm_bt<0><<<dim3(24,32),blk,0,stream>>>(hb, qkvw, qkv, nullptr, nullptr, nullptr, nullptr, TOK, QKS, DIM);
  vtrk<<<dim3(SEQ/64,32),blk,0,stream>>>(qkv + 2048, vt);
  attnk<<<dim3(32,32),blk,0,stream>>>(qkv, qkv + 1024, vt, ab);
  gemm_bt<2><<<dim3(8,32),blk,0,stream>>>(ab, ow, nullptr, x2, nullptr, x, nullptr, TOK, DIM, DIM);
  lnk<<<TOK,blk,0,stream>>>(x2, ln2_g, ln2_b, hb);
  gemm256<1><<<256, 512, 0, stream>>>(hb, fiw, ub, fi_b, nullptr, TOK, FFN_N, DIM);
  gemm256<0><<<256, 512, 0, stream>>>(ub, sww, a1, nullptr, nullptr, TOK, FFN_N, FFN_N);
  gemm256<4><<<256, 512, 0, stream>>>(ub, swv, gb, nullptr, a1, TOK, FFN_N, FFN_N);
  gemm_bt<3><<<dim3(8,32),blk,0,stream>>>(gb, fow, nullptr, out, fo_b, x2, nullptr, TOK, DIM, FFN_N);
}

// Round 10
// 558.931 us; speedup vs baseline: 1.0468x; 1.0468x over previous
//
#include <hip/hip_runtime.h>
#include <hip/hip_bf16.h>

#define TOK 4096
#define DIM 1024
#define FFN_N 4096
#define SEQ 2048
#define HD 64
#define QKS 3072   // fused QKV row stride

using short8 = __attribute__((ext_vector_type(8))) short;
using short4v = __attribute__((ext_vector_type(4))) short;
using f32x4 = __attribute__((ext_vector_type(4))) float;

__device__ __forceinline__ short f2b(float f){
  return __builtin_bit_cast(short, __float2bfloat16(f));
}
__device__ __forceinline__ float b2f(short s){
  return __bfloat162float(__builtin_bit_cast(__hip_bfloat16, s));
}
__device__ __forceinline__ unsigned cvtpk(float lo, float hi){
  unsigned r;
  asm("v_cvt_pk_bf16_f32 %0, %1, %2" : "=v"(r) : "v"(lo), "v"(hi));
  return r;
}

__device__ __forceinline__ void gl_lds16(const short* g, short* l){
  __builtin_amdgcn_global_load_lds(
      (const __attribute__((address_space(1))) unsigned int*)g,
      (__attribute__((address_space(3))) unsigned int*)l, 16, 0, 0);
}

#define BARRAW() asm volatile("s_barrier" ::: "memory")
#define VMCNT(n) asm volatile("s_waitcnt vmcnt(" #n ")" ::: "memory")

// ---------------- cast f32 -> bf16 ----------------
__global__ __launch_bounds__(256) void castk(const float* __restrict__ src,
                                             short* __restrict__ dst, int n){
  int stride = gridDim.x*256*4;
  for (int i = (blockIdx.x*256 + threadIdx.x)*4; i < n; i += stride){
    float4 v = *reinterpret_cast<const float4*>(src + i);
    short4v o; o[0]=f2b(v.x); o[1]=f2b(v.y); o[2]=f2b(v.z); o[3]=f2b(v.w);
    *reinterpret_cast<short4v*>(dst + i) = o;
  }
}

// ---------------- layernorm f32 -> bf16 ----------------
__global__ __launch_bounds__(256) void lnk(const float* __restrict__ x,
                                           const float* __restrict__ g,
                                           const float* __restrict__ b,
                                           short* __restrict__ out){
  int row = blockIdx.x;
  int t = threadIdx.x;
  const float* xr = x + (size_t)row*DIM;
  float4 v = *reinterpret_cast<const float4*>(xr + t*4);
  float s = v.x+v.y+v.z+v.w;
  float s2 = v.x*v.x+v.y*v.y+v.z*v.z+v.w*v.w;
  #pragma unroll
  for (int off=1; off<64; off<<=1){ s += __shfl_xor(s,off); s2 += __shfl_xor(s2,off); }
  __shared__ float as_[4], as2_[4];
  if ((t&63)==0){ as_[t>>6]=s; as2_[t>>6]=s2; }
  __syncthreads();
  s = as_[0]+as_[1]+as_[2]+as_[3];
  s2 = as2_[0]+as2_[1]+as2_[2]+as2_[3];
  float mu = s * (1.0f/DIM);
  float var = s2 * (1.0f/DIM) - mu*mu;
  float r = rsqrtf(var + 1e-5f);
  float4 gv = *reinterpret_cast<const float4*>(g + t*4);
  float4 bv = *reinterpret_cast<const float4*>(b + t*4);
  short4v o;
  o[0]=f2b((v.x-mu)*r*gv.x + bv.x);
  o[1]=f2b((v.y-mu)*r*gv.y + bv.y);
  o[2]=f2b((v.z-mu)*r*gv.z + bv.z);
  o[3]=f2b((v.w-mu)*r*gv.w + bv.w);
  *reinterpret_cast<short4v*>(out + (size_t)row*DIM + t*4) = o;
}

// ---------------- GEMM C = A @ B^T (+epilogue), m97 structure (small-N shapes) ----------------
template<int MODE>
__global__ __launch_bounds__(256,2) void gemm_bt(
    const short* __restrict__ A, const short* __restrict__ Bt,
    short* __restrict__ Cb, float* __restrict__ Cf,
    const float* __restrict__ bias, const float* __restrict__ resid,
    const short* __restrict__ aux,
    int M, int N, int K)
{
  __shared__ __align__(16) short Al[128*32];
  __shared__ __align__(16) short Bl[128*32];
  const int tid = threadIdx.x, lane = tid & 63, w = tid >> 6;
  const int wr = w >> 1, wc = w & 1;
  const int bx = blockIdx.x, by = blockIdx.y;

  const short* ga0 = A  + (size_t)(by*128 + w*32 + (lane>>2))*K + (lane&3)*8;
  const short* gb0 = Bt + (size_t)(bx*128 + w*32 + (lane>>2))*K + (lane&3)*8;
  short* la0 = &Al[w*32*32];
  short* lb0 = &Bl[w*32*32];

  f32x4 acc[4][4] = {};

  for (int k0 = 0; k0 < K; k0 += 32){
    __syncthreads();
    gl_lds16(ga0 + k0,                 la0);
    gl_lds16(ga0 + k0 + (size_t)16*K,  la0 + 16*32);
    gl_lds16(gb0 + k0,                 lb0);
    gl_lds16(gb0 + k0 + (size_t)16*K,  lb0 + 16*32);
    __syncthreads();
    short8 af[4], bf[4];
    #pragma unroll
    for (int m=0;m<4;m++)
      af[m] = *reinterpret_cast<const short8*>(&Al[(wr*64 + m*16 + (lane&15))*32 + (lane>>4)*8]);
    #pragma unroll
    for (int n=0;n<4;n++)
      bf[n] = *reinterpret_cast<const short8*>(&Bl[(wc*64 + n*16 + (lane&15))*32 + (lane>>4)*8]);
    #pragma unroll
    for (int m=0;m<4;m++)
      #pragma unroll
      for (int n=0;n<4;n++)
        acc[m][n] = __builtin_amdgcn_mfma_f32_16x16x32_bf16(af[m], bf[n], acc[m][n], 0,0,0);
  }

  #pragma unroll
  for (int m=0;m<4;m++){
    #pragma unroll
    for (int n=0;n<4;n++){
      #pragma unroll
      for (int j=0;j<4;j++){
        int r = by*128 + wr*64 + m*16 + ((lane>>4)<<2) + j;
        int c = bx*128 + wc*64 + n*16 + (lane&15);
        float v = acc[m][n][j];
        if (MODE==1 || MODE==3) v += bias[c];
        size_t idx = (size_t)r*N + c;
        if (MODE==4){
          float a = b2f(aux[idx]);
          float sg = a / (1.0f + __expf(-a));
          Cb[idx] = f2b(sg * v);
        } else if (MODE<=1) {
          Cb[idx] = f2b(v);
        } else {
          Cf[idx] = resid[idx] + v;
        }
      }
    }
  }
}

// ---------------- 256x256 GEMM: 2 barriers/K-tile, counted vmcnt (unchanged from R8) ----------------
template<int MODE>
__global__ __launch_bounds__(512,2) void gemm256(
    const short* __restrict__ A, const short* __restrict__ Bt,
    short* __restrict__ Cb,
    const float* __restrict__ bias, const short* __restrict__ aux,
    int M, int N, int K)
{
  __shared__ __align__(16) short L[65536];
  const int tid = threadIdx.x, lane = tid&63, w = tid>>6;
  const int q15 = lane&15, h8 = lane>>4;
  const int wm = w>>2, wn = w&3;
  const int NT = K>>6;

  int bid = blockIdx.x;
  int wg = (bid&7)*(gridDim.x>>3) + (bid>>3);
  const int by = wg >> 4, bx = wg & 15;

  const int isub = w*8 + (lane>>3);
  const int koff = ((lane&7) ^ ((lane>>3)&7))*8;

  const short* gA[2][2]; const short* gB[2][2];
  #pragma unroll
  for (int hh=0; hh<2; hh++){
    #pragma unroll
    for (int j=0; j<2; j++){
      int i = j*64 + isub;
      int Ra = by*256 + (i>>6)*128 + hh*64 + (i&63);
      gA[hh][j] = A + (size_t)Ra*K + koff;
      int Rb = bx*256 + (i>>5)*64 + hh*32 + (i&31);
      gB[hh][j] = Bt + (size_t)Rb*K + koff;
    }
  }

  auto stA = [&](int db, int hh, int j, int kt){
    gl_lds16(gA[hh][j] + (size_t)kt*64, &L[db*32768 + hh*8192 + j*4096 + w*512]);
  };
  auto stB = [&](int db, int hh, int j, int kt){
    gl_lds16(gB[hh][j] + (size_t)kt*64, &L[db*32768 + (2+hh)*8192 + j*4096 + w*512]);
  };
  auto rdA = [&](int db, int mh, int m, int ks)->short8{
    int i = wm*64 + m*16 + q15;
    int ch = (ks*4 + h8) ^ (i&7);
    return *reinterpret_cast<const short8*>(&L[db*32768 + mh*8192 + i*64 + ch*8]);
  };
  auto rdB = [&](int db, int nh, int n, int ks)->short8{
    int i = wn*32 + n*16 + q15;
    int ch = (ks*4 + h8) ^ (i&7);
    return *reinterpret_cast<const short8*>(&L[db*32768 + (2+nh)*8192 + i*64 + ch*8]);
  };

  f32x4 acc[8][4] = {};
  short8 af[4][2], bf0[2][2], bf1[2][2];

#define MFMA_QUAD(MH, NH, BF)                                                  \
  __builtin_amdgcn_s_setprio(1);                                               \
  _Pragma("unroll")                                                            \
  for (int m=0;m<4;m++){                                                       \
    _Pragma("unroll")                                                          \
    for (int n=0;n<2;n++){                                                     \
      acc[(MH)*4+m][(NH)*2+n] = __builtin_amdgcn_mfma_f32_16x16x32_bf16(       \
          af[m][0], BF[n][0], acc[(MH)*4+m][(NH)*2+n], 0,0,0);                 \
      acc[(MH)*4+m][(NH)*2+n] = __builtin_amdgcn_mfma_f32_16x16x32_bf16(       \
          af[m][1], BF[n][1], acc[(MH)*4+m][(NH)*2+n], 0,0,0);                 \
    }                                                                          \
  }                                                                            \
  __builtin_amdgcn_s_setprio(0);

  stA(0,0,0,0); stA(0,0,1,0);
  stB(0,0,0,0); stB(0,0,1,0);
  stA(0,1,0,0); stA(0,1,1,0);
  stB(0,1,0,0); stB(0,1,1,0);
  VMCNT(4);
  BARRAW();

  for (int t = 0; t < NT; ++t){
    const int db = t&1;
    const bool pf = (t+1 < NT);

    #pragma unroll
    for (int m=0;m<4;m++){ af[m][0]=rdA(db,0,m,0); af[m][1]=rdA(db,0,m,1); }
    #pragma unroll
    for (int n=0;n<2;n++){ bf0[n][0]=rdB(db,0,n,0); bf0[n][1]=rdB(db,0,n,1); }
    if (pf){ stA(db^1,0,0,t+1); stA(db^1,0,1,t+1);
             stB(db^1,0,0,t+1); stB(db^1,0,1,t+1); }
    MFMA_QUAD(0,0,bf0);

    if (pf){ VMCNT(4); } else { VMCNT(0); }
    BARRAW();

    #pragma unroll
    for (int n=0;n<2;n++){ bf1[n][0]=rdB(db,1,n,0); bf1[n][1]=rdB(db,1,n,1); }
    if (pf){ stA(db^1,1,0,t+1); stA(db^1,1,1,t+1);
             stB(db^1,1,0,t+1); stB(db^1,1,1,t+1); }
    MFMA_QUAD(0,1,bf1);

    #pragma unroll
    for (int m=0;m<4;m++){ af[m][0]=rdA(db,1,m,0); af[m][1]=rdA(db,1,m,1); }
    MFMA_QUAD(1,1,bf1);
    MFMA_QUAD(1,0,bf0);

    if (pf){ VMCNT(4); }
    BARRAW();
  }

  #pragma unroll
  for (int mq=0;mq<8;mq++){
    #pragma unroll
    for (int nq=0;nq<4;nq++){
      #pragma unroll
      for (int jj=0;jj<4;jj++){
        int r = by*256 + wm*128 + mq*16 + h8*4 + jj;
        int c = bx*256 + wn*64  + nq*16 + q15;
        float v = acc[mq][nq][jj];
        if (MODE==1) v += bias[c];
        size_t idx = (size_t)r*N + c;
        if (MODE==4){
          float a = b2f(aux[idx]);
          float sg = a / (1.0f + __expf(-a));
          Cb[idx] = f2b(sg * v);
        } else {
          Cb[idx] = f2b(v);
        }
      }
    }
  }
#undef MFMA_QUAD
}

// ---------------- V transpose: per (b,h), [SEQ][QKS] -> [64][SEQ] (R8 version) ----------------
__global__ __launch_bounds__(256) void vtrk(const short* __restrict__ V,
                                            short* __restrict__ Vt){
  __shared__ __align__(16) short T[64*72];
  const int tid = threadIdx.x;
  const int bh = blockIdx.y;
  const int b = bh >> 4, hd = bh & 15;
  const int t0 = blockIdx.x * 64;
  const short* src = V + (size_t)b*SEQ*QKS + (size_t)hd*HD;

  const int r = tid>>2, c = tid&3;
  short8 a0 = *reinterpret_cast<const short8*>(src + (size_t)(t0+r)*QKS + c*8);
  short8 a1 = *reinterpret_cast<const short8*>(src + (size_t)(t0+r)*QKS + (c+4)*8);
  *reinterpret_cast<short8*>(&T[r*72 + c*8]) = a0;
  *reinterpret_cast<short8*>(&T[r*72 + (c+4)*8]) = a1;
  __syncthreads();

  short* dst = Vt + (size_t)bh*HD*SEQ;
  #pragma unroll
  for (int dd=0; dd<2; dd++){
    int d = (tid>>3) + dd*32;
    int tc = tid&7;
    short8 o;
    #pragma unroll
    for (int j=0;j<8;j++) o[j] = T[(tc*8+j)*72 + d];
    *reinterpret_cast<short8*>(dst + (size_t)d*SEQ + t0 + tc*8) = o;
  }
}

// ---------------- flash attention: QBLK=128, 8 waves, KVBLK=64 (R8 schedule) ----------------
// Each wave owns 16 q-rows; K/V staged 1 gl_lds per wave each (chunk-XOR source);
// staged tile feeds 2x the MFMA work vs R8's 4-wave version.
__global__ __launch_bounds__(512) void attnk(
    const short* __restrict__ Q, const short* __restrict__ K,
    const short* __restrict__ Vt, short* __restrict__ O)
{
  __shared__ __align__(16) short Kl[64*64];
  __shared__ __align__(16) short Vl[64*64];
  __shared__ __align__(16) short Pl[8*16*72];

  const int tid = threadIdx.x, lane = tid&63, w = tid>>6;   // w in 0..7
  const int h = lane>>4, q15 = lane&15;
  const int bh = blockIdx.y;
  const int b = bh >> 4, hd = bh & 15;
  const int q0 = blockIdx.x * 128;
  const size_t base  = (size_t)b*SEQ*QKS + (size_t)hd*HD;
  const size_t obase = (size_t)b*SEQ*DIM + (size_t)hd*HD;
  const size_t vbase = (size_t)bh*HD*SEQ;

  short8 aq[2];
  {
    int qrow = q0 + w*16 + q15;
    const short* qp = Q + base + (size_t)qrow*QKS + h*8;
    aq[0] = *reinterpret_cast<const short8*>(qp);
    aq[1] = *reinterpret_cast<const short8*>(qp + 32);
  }

  float mrun = -1e30f, lrun = 0.f;
  f32x4 o[4] = {};

  // staging: wave w stages rows w*8 .. w*8+7 (K: kv rows; V: d rows of V^T)
  const int srow = lane>>3;                     // 0..7
  const int schunk = (lane&7) ^ srow;           // pre-swizzled source chunk
  const short* kg = K  + base  + (size_t)(w*8 + srow)*QKS + schunk*8;
  const short* vg = Vt + vbase + (size_t)(w*8 + srow)*SEQ + schunk*8;
  short* kl = &Kl[(w*8)*64];
  short* vl = &Vl[(w*8)*64];

  short* plw = &Pl[w*16*72];
  const int xk = (q15&7);

  for (int kv0 = 0; kv0 < SEQ; kv0 += 64){
    __syncthreads();
    gl_lds16(kg + (size_t)kv0*QKS, kl);
    gl_lds16(vg + kv0, vl);
    __syncthreads();

    f32x4 s[4];
    #pragma unroll
    for (int nt=0; nt<4; nt++){
      const short8 kf0 = *reinterpret_cast<const short8*>(
          &Kl[(nt*16+q15)*64 + ((h    ^ xk)*8)]);
      const short8 kf1 = *reinterpret_cast<const short8*>(
          &Kl[(nt*16+q15)*64 + (((4+h)^ xk)*8)]);
      f32x4 t = {};
      t = __builtin_amdgcn_mfma_f32_16x16x32_bf16(kf0, aq[0], t, 0,0,0);
      t = __builtin_amdgcn_mfma_f32_16x16x32_bf16(kf1, aq[1], t, 0,0,0);
      s[nt] = t * 0.125f;
    }

    float pm = s[0][0];
    #pragma unroll
    for (int nt=0; nt<4; nt++)
      #pragma unroll
      for (int j=0; j<4; j++) pm = fmaxf(pm, s[nt][j]);
    pm = fmaxf(pm, __shfl_xor(pm, 16));
    pm = fmaxf(pm, __shfl_xor(pm, 32));

    float mn = fmaxf(mrun, pm);
    float al = __expf(mrun - mn);
    mrun = mn;
    float rs = 0.f;
    #pragma unroll
    for (int nt=0; nt<4; nt++)
      #pragma unroll
      for (int j=0; j<4; j++){
        s[nt][j] = __expf(s[nt][j] - mn);
        rs += s[nt][j];
      }
    rs += __shfl_xor(rs, 16);
    rs += __shfl_xor(rs, 32);
    lrun = lrun*al + rs;

    float alj[4];
    #pragma unroll
    for (int j=0;j<4;j++) alj[j] = __shfl(al, 4*h + j);
    #pragma unroll
    for (int dt=0;dt<4;dt++)
      #pragma unroll
      for (int j=0;j<4;j++) o[dt][j] *= alj[j];

    #pragma unroll
    for (int nt=0;nt<4;nt++){
      uint2 u;
      u.x = cvtpk(s[nt][0], s[nt][1]);
      u.y = cvtpk(s[nt][2], s[nt][3]);
      *reinterpret_cast<uint2*>(&plw[q15*72 + nt*16 + 4*h]) = u;
    }
    asm volatile("s_waitcnt lgkmcnt(0)" ::: "memory");
    const short8 ap0 = *reinterpret_cast<const short8*>(&plw[q15*72 +      h*8]);
    const short8 ap1 = *reinterpret_cast<const short8*>(&plw[q15*72 + 32 + h*8]);

    #pragma unroll
    for (int dt=0;dt<4;dt++){
      const short8 vf0 = *reinterpret_cast<const short8*>(
          &Vl[(dt*16+q15)*64 + ((h    ^ xk)*8)]);
      const short8 vf1 = *reinterpret_cast<const short8*>(
          &Vl[(dt*16+q15)*64 + (((4+h)^ xk)*8)]);
      o[dt] = __builtin_amdgcn_mfma_f32_16x16x32_bf16(ap0, vf0, o[dt], 0,0,0);
      o[dt] = __builtin_amdgcn_mfma_f32_16x16x32_bf16(ap1, vf1, o[dt], 0,0,0);
    }
  }

  float rl[4];
  #pragma unroll
  for (int j=0;j<4;j++) rl[j] = 1.0f / __shfl(lrun, 4*h + j);
  #pragma unroll
  for (int dt=0;dt<4;dt++)
    #pragma unroll
    for (int j=0;j<4;j++){
      int qrow = q0 + w*16 + 4*h + j;
      O[obase + (size_t)qrow*DIM + dt*16 + q15] = f2b(o[dt][j]*rl[j]);
    }
}

extern "C" void kernel_launch(void* const* d_in, const int* in_sizes, int n_in,
                              void* d_out, int out_size, void* d_ws, size_t ws_size,
                              hipStream_t stream) {
  const float* x     = (const float*)d_in[0];
  const float* ln1_g = (const float*)d_in[1];
  const float* ln1_b = (const float*)d_in[2];
  const float* q_w   = (const float*)d_in[3];
  const float* k_w   = (const float*)d_in[4];
  const float* v_w   = (const float*)d_in[5];
  const float* o_w   = (const float*)d_in[6];
  const float* ln2_g = (const float*)d_in[7];
  const float* ln2_b = (const float*)d_in[8];
  const float* fi_w  = (const float*)d_in[9];
  const float* fi_b  = (const float*)d_in[10];
  const float* sw_w  = (const float*)d_in[11];
  const float* sw_v  = (const float*)d_in[12];
  const float* fo_w  = (const float*)d_in[13];
  const float* fo_b  = (const float*)d_in[14];
  float* out = (float*)d_out;

  char* W = (char*)d_ws;
  const size_t MB = 1024*1024;
  short* qkvw = (short*)(W +   0*MB);   // fused [3072][1024]
  short* ow   = (short*)(W +   6*MB);
  short* fiw  = (short*)(W +   8*MB);
  short* sww  = (short*)(W +  16*MB);
  short* swv  = (short*)(W +  48*MB);
  short* fow  = (short*)(W +  80*MB);
  short* hb   = (short*)(W +  88*MB);
  short* qkv  = (short*)(W +  96*MB);   // [4096][3072] = 24MB
  short* ab   = (short*)(W + 120*MB);
  float* x2   = (float*)(W + 128*MB);
  short* ub   = (short*)(W + 144*MB);
  short* gb   = (short*)(W + 176*MB);
  short* a1   = (short*)(W +  96*MB);   // alias qkv+ab (dead by SwiGLU time)
  short* vt   = (short*)(W + 144*MB);   // alias ub (dead before FFN-in)

  dim3 blk(256);
  castk<<<1024,blk,0,stream>>>(q_w, qkvw,             1024*1024);
  castk<<<1024,blk,0,stream>>>(k_w, qkvw + 1024*1024, 1024*1024);
  castk<<<1024,blk,0,stream>>>(v_w, qkvw + 2048*1024, 1024*1024);
  castk<<<1024,blk,0,stream>>>(o_w, ow, 1024*1024);
  castk<<<2048,blk,0,stream>>>(fi_w, fiw, 4096*1024);
  castk<<<2048,blk,0,stream>>>(sw_w, sww, 4096*4096);
  castk<<<2048,blk,0,stream>>>(sw_v, swv, 4096*4096);
  castk<<<2048,blk,0,stream>>>(fo_w, fow, 1024*4096);

  lnk<<<TOK,blk,0,stream>>>(x, ln1_g, ln1_b, hb);
  gemm_bt<0><<<dim3(24,32),blk,0,stream>>>(hb, qkvw, qkv, nullptr, nullptr, nullptr, nullptr, TOK, QKS, DIM);
  vtrk<<<dim3(SEQ/64,32),blk,0,stream>>>(qkv + 2048, vt);
  attnk<<<dim3(SEQ/128,32), 512, 0, stream>>>(qkv, qkv + 1024, vt, ab);
  gemm_bt<2><<<dim3(8,32),blk,0,stream>>>(ab, ow, nullptr, x2, nullptr, x, nullptr, TOK, DIM, DIM);
  lnk<<<TOK,blk,0,stream>>>(x2, ln2_g, ln2_b, hb);
  gemm256<1><<<256, 512, 0, stream>>>(hb, fiw, ub, fi_b, nullptr, TOK, FFN_N, DIM);
  gemm256<0><<<256, 512, 0, stream>>>(ub, sww, a1, nullptr, nullptr, TOK, FFN_N, FFN_N);
  gemm256<4><<<256, 512, 0, stream>>>(ub, swv, gb, nullptr, a1, TOK, FFN_N, FFN_N);
  gemm_bt<3><<<dim3(8,32),blk,0,stream>>>(gb, fow, nullptr, out, fo_b, x2, nullptr, TOK, DIM, FFN_N);
}